// Round 9
// baseline (110.285 us; speedup 1.0000x reference)
//
#include <hip/hip_runtime.h>

// ---------------------------------------------------------------------------
// Output depends ONLY on positions[0:64]. ~25 MFLOP total.
//
// R9: 2 kernels.
//  AB (64 blocks = (row-group bg, col-slice j0) pairs): replicated backbone
//     (winner/h1/h2 for own 8 rows), gf own 8 rows x 256 cols vs full W3 in
//     LDS (R8 a_gf verbatim), THEN reuse W3's LDS for the 32KB Wn1 slice and
//     compute the tpart slice (R8 k2_tpart verbatim, gf from local LDS --
//     kills the gf_ws global round-trip AND one launch slot).
//  CD (4 blocks = heads): replicated tbar+agg (Wn2 via two 64KB LDS halves)
//     + Wh1[k] heads + final dot.                  [R8 cd_head, verbatim]
//
// BIT-EXACTNESS: harness demands bit-exact bf16 (R1 failed by one ulp).
// Every per-output accumulation keeps the VERBATIM expression structure and
// ascending chunk order from rounds that scored absmax 0.0. Do not
// reassociate. Spill discipline (R6 lesson): each accumulator's live range
// stays inside its phase; no LDS rotation with live accumulators.
// ---------------------------------------------------------------------------

__device__ __forceinline__ void async_cp16(const float* g, float* l) {
    __builtin_amdgcn_global_load_lds(
        (const __attribute__((address_space(1))) void*)g,
        (__attribute__((address_space(3))) void*)l, 16, 0, 0);
}
// contiguous: nfloats multiple of 256; 1 inst moves 256 floats (64 lanes x 16B)
__device__ __forceinline__ void stage_contig(const float* g, float* l, int nfloats, int tid) {
    const int lane = tid & 63, wv = tid >> 6;
    const int ninst = nfloats >> 8;
    for (int i = wv; i < ninst; i += 4)
        async_cp16(g + i*256 + lane*4, l + i*256);
}
// 32-col slice of row-major [nrows][ld] at col j0 -> LDS [r][32]
__device__ __forceinline__ void stage_slice32(const float* g, float* l, int ld, int j0, int nrows, int tid) {
    const int lane = tid & 63, wv = tid >> 6;
    const int r = lane >> 3, c4 = (lane & 7) << 2;
    const int ninst = nrows >> 3;
    for (int i = wv; i < ninst; i += 4)
        async_cp16(g + (i*8 + r)*ld + j0 + c4, l + i*256);
}

// ---- AB (64 blocks): backbone + gf (full W3 in LDS) + tpart slice ---------
#define AB_SMEM_BYTES (32768*4)   // full W3, later first 8192 floats = Wn1 slice

__global__ __launch_bounds__(256) void ab_tpart(
    const float* __restrict__ positions, const float* __restrict__ grid_pts,
    const float* __restrict__ W1, const float* __restrict__ b1,
    const float* __restrict__ W2, const float* __restrict__ b2,
    const float* __restrict__ W3, const float* __restrict__ b3,
    const float* __restrict__ Wn1, const float* __restrict__ bn1,
    float* __restrict__ tpart_ws)                           // (8,256)
{
    extern __shared__ float w3s[];                          // 128 KB
    __shared__ float pos_s[192], grid_s[192], w1_s[192], b1_s[64];
    __shared__ int   idx_s[64], win_s[8];
    __shared__ __align__(16) float h1s[8*64];
    __shared__ __align__(16) float h2s[8*128];
    __shared__ __align__(16) float gfs[8*256];
    __shared__ float r_s[256];

    const int tid = threadIdx.x;
    const int bg  = blockIdx.x >> 3;                        // row-group 0..7
    const int j0  = (blockIdx.x & 7) * 32;                  // col-slice
    const int jl  = tid & 31, tt5 = tid >> 5;

    stage_contig(W3, w3s, 32768, tid);                      // async at entry
    if (tid < 192) { pos_s[tid] = positions[tid]; grid_s[tid] = grid_pts[tid]; w1_s[tid] = W1[tid]; }
    if (tid >= 192) b1_s[tid - 192] = b1[tid - 192];
    const float bb2  = b2[tid & 127];
    const float bb3  = b3[tid];
    const float bbn1 = bn1[j0 + jl];
    __syncthreads();                                        // drain 1

    if (tid < 64) {                      // verbatim argmin
        const float px = pos_s[tid*3], py = pos_s[tid*3+1], pz = pos_s[tid*3+2];
        float best = 3.4e38f; int bi = 0;
        for (int g = 0; g < 64; ++g) {
            const float dx = px - grid_s[g*3];
            const float dy = py - grid_s[g*3+1];
            const float dz = pz - grid_s[g*3+2];
            const float d2 = dx*dx + dy*dy + dz*dz;
            if (d2 < best) { best = d2; bi = g; }
        }
        idx_s[tid] = bi;
    }
    __syncthreads();
    if (tid < 8) {                       // verbatim winner rule, own 8 rows
        const int g = bg*8 + tid;
        int m = -1;
        for (int i = 0; i < 64; ++i) if (idx_s[i] == g) m = i;
        win_s[tid] = m;
    }
    __syncthreads();

    // h1 own 8 rows (512 outs): verbatim expression
    #pragma unroll
    for (int u = 0; u < 2; ++u) {
        const int e  = tid + u*256;
        const int lr = e >> 6, k = e & 63;
        int r = win_s[lr]; if (r < 0) r = 0;
        const float acc = b1_s[k] + pos_s[r*3]*w1_s[k] + pos_s[r*3+1]*w1_s[64+k]
                                  + pos_s[r*3+2]*w1_s[128+k];
        h1s[lr*64 + k] = fmaxf(acc, 0.f);
    }
    __syncthreads();

    // h2 own 8 rows: verbatim chunk structure; W2 via chunked GLOBAL loads
    {
        const int d = tid & 127, t0 = tid >> 7;
        float acc[4];
        #pragma unroll
        for (int m = 0; m < 4; ++m) acc[m] = bb2;
        for (int kc = 0; kc < 64; kc += 16) {
            float w[16];
            #pragma unroll
            for (int u = 0; u < 16; ++u) w[u] = W2[(kc+u)*128 + d];
            #pragma unroll
            for (int u = 0; u < 16; u += 4) {
                #pragma unroll
                for (int m = 0; m < 4; ++m) {
                    const float4 h4 = *(const float4*)&h1s[(t0 + 2*m)*64 + kc + u];
                    acc[m] += h4.x*w[u] + h4.y*w[u+1] + h4.z*w[u+2] + h4.w*w[u+3];
                }
            }
        }
        #pragma unroll
        for (int m = 0; m < 4; ++m)
            h2s[(t0 + 2*m)*128 + d] = fmaxf(acc[m], 0.f);
    }
    __syncthreads();

    // gf own 8 rows x all 256 cols: verbatim accumulation, W3 from LDS.
    // ag[] retires to LDS (gfs) before the tpart phase -- no cross-phase
    // register pressure (R6 lesson).
    {
        const int j = tid;
        float ag[8];
        #pragma unroll
        for (int t = 0; t < 8; ++t) ag[t] = 0.f;
        for (int dc = 0; dc < 128; dc += 16) {
            float w[16];
            #pragma unroll
            for (int u = 0; u < 16; ++u) w[u] = w3s[(dc+u)*256 + j];
            #pragma unroll
            for (int u = 0; u < 16; u += 4) {
                #pragma unroll
                for (int t = 0; t < 8; ++t) {
                    const float4 h4 = *(const float4*)&h2s[t*128 + dc + u];
                    ag[t] += h4.x*w[u] + h4.y*w[u+1] + h4.z*w[u+2] + h4.w*w[u+3];
                }
            }
        }
        #pragma unroll
        for (int t = 0; t < 8; ++t)
            gfs[t*256 + tid] = (win_s[t] >= 0) ? (ag[t] + bb3) : 0.f;
    }
    __syncthreads();                                        // W3 reads done
    stage_slice32(Wn1, w3s, 256, j0, 256, tid);             // Wn1 slice -> LDS
    __syncthreads();                                        // drain 2

    // tpart slice: verbatim R8 k2_tpart accumulation (gf from local LDS)
    {
        float acc = bbn1;
        for (int cc = 0; cc < 256; cc += 32) {
            float w[32];
            #pragma unroll
            for (int u = 0; u < 32; ++u) w[u] = w3s[(cc+u)*32 + jl];
            #pragma unroll
            for (int u = 0; u < 32; u += 4) {
                const float4 g4 = *(const float4*)&gfs[tt5*256 + cc + u];
                acc += g4.x*w[u] + g4.y*w[u+1] + g4.z*w[u+2] + g4.w*w[u+3];
            }
        }
        r_s[tid] = fmaxf(acc, 0.f);
    }
    __syncthreads();
    if (tt5 == 0) {                      // verbatim two-level sum, level 1
        float ps = 0.f;
        #pragma unroll
        for (int t = 0; t < 8; ++t) ps += r_s[t*32 + jl];
        tpart_ws[bg*256 + j0 + jl] = ps;
    }
}

// ---- CD (4 blocks = heads): tbar+agg+heads+out (R8 verbatim) --------------
#define CD_SMEM_BYTES (32768*4)

__global__ __launch_bounds__(256) void cd_head(
    const float* __restrict__ Wn2, const float* __restrict__ bn2,
    const float* __restrict__ Wh1, const float* __restrict__ bh1,
    const float* __restrict__ Wh2, const float* __restrict__ bh2,
    const float* __restrict__ tpart_ws,                     // (8,256)
    float* __restrict__ out)                                // (4)
{
    extern __shared__ float sm[];
    __shared__ __align__(16) float tp_s[2048];
    __shared__ __align__(16) float tbar_s[256];
    __shared__ __align__(16) float agg_s[256];
    __shared__ __align__(16) float h1h_s[128];
    __shared__ __align__(16) float wh2_s[128];

    float* bufA = sm;            // 16384 floats (64 KB)
    float* bufB = sm + 16384;    // 16384 floats

    const int tid = threadIdx.x;
    const int k   = blockIdx.x;

    stage_contig(tpart_ws, tp_s, 2048, tid);
    stage_contig(Wn2,          bufA, 16384, tid);           // rows 0..63
    stage_contig(Wn2 + 16384,  bufB, 16384, tid);           // rows 64..127
    const float bbn2  = bn2[tid];
    const float bbh1k = (tid < 128) ? bh1[k*128 + tid] : 0.f;
    if (tid < 128) wh2_s[tid] = Wh2[k*128 + tid];
    const float bbh2k = bh2[k];
    __syncthreads();                                        // A

    {   // tbar: verbatim (q ascending, then *1/64)
        float tb = 0.f;
        #pragma unroll
        for (int q = 0; q < 8; ++q) tb += tp_s[q*256 + tid];
        tbar_s[tid] = tb * (1.f/64.f);
    }
    __syncthreads();                                        // B

    // agg: verbatim chunk structure, jc ascending 0..255, thread c = tid
    float acc = bbn2;
    for (int jc = 0; jc < 64; jc += 32) {                   // bufA
        float w[32];
        #pragma unroll
        for (int u = 0; u < 32; ++u) w[u] = bufA[(jc+u)*256 + tid];
        #pragma unroll
        for (int u = 0; u < 32; u += 4) {
            const float4 t4 = *(const float4*)&tbar_s[jc + u];
            acc += t4.x*w[u] + t4.y*w[u+1] + t4.z*w[u+2] + t4.w*w[u+3];
        }
    }
    __syncthreads();                                        // C (bufA free)
    stage_contig(Wn2 + 32768, bufA, 16384, tid);            // rows 128..191
    for (int jc = 64; jc < 128; jc += 32) {                 // bufB
        float w[32];
        #pragma unroll
        for (int u = 0; u < 32; ++u) w[u] = bufB[(jc-64+u)*256 + tid];
        #pragma unroll
        for (int u = 0; u < 32; u += 4) {
            const float4 t4 = *(const float4*)&tbar_s[jc + u];
            acc += t4.x*w[u] + t4.y*w[u+1] + t4.z*w[u+2] + t4.w*w[u+3];
        }
    }
    __syncthreads();                                        // D (bufB free)
    stage_contig(Wn2 + 49152, bufB, 16384, tid);            // rows 192..255
    for (int jc = 128; jc < 192; jc += 32) {                // bufA
        float w[32];
        #pragma unroll
        for (int u = 0; u < 32; ++u) w[u] = bufA[(jc-128+u)*256 + tid];
        #pragma unroll
        for (int u = 0; u < 32; u += 4) {
            const float4 t4 = *(const float4*)&tbar_s[jc + u];
            acc += t4.x*w[u] + t4.y*w[u+1] + t4.z*w[u+2] + t4.w*w[u+3];
        }
    }
    __syncthreads();                                        // E
    for (int jc = 192; jc < 256; jc += 32) {                // bufB
        float w[32];
        #pragma unroll
        for (int u = 0; u < 32; ++u) w[u] = bufB[(jc-192+u)*256 + tid];
        #pragma unroll
        for (int u = 0; u < 32; u += 4) {
            const float4 t4 = *(const float4*)&tbar_s[jc + u];
            acc += t4.x*w[u] + t4.y*w[u+1] + t4.z*w[u+2] + t4.w*w[u+3];
        }
    }
    agg_s[tid] = acc;
    __syncthreads();                                        // F (bufs free)
    stage_contig(Wh1 + k*32768,         bufA, 16384, tid);  // Wh1[k] rows 0..127
    stage_contig(Wh1 + k*32768 + 16384, bufB, 16384, tid);  // rows 128..255
    __syncthreads();                                        // G

    if (tid < 128) {   // heads: verbatim chunk structure, cc ascending
        const int d = tid;
        float a = bbh1k;
        for (int cc = 0; cc < 128; cc += 16) {
            float wa[16];
            #pragma unroll
            for (int u = 0; u < 16; ++u) wa[u] = bufA[(cc+u)*128 + d];
            #pragma unroll
            for (int u = 0; u < 16; u += 4) {
                const float4 a4 = *(const float4*)&agg_s[cc + u];
                a += a4.x*wa[u] + a4.y*wa[u+1] + a4.z*wa[u+2] + a4.w*wa[u+3];
            }
        }
        for (int cc = 128; cc < 256; cc += 16) {
            float wa[16];
            #pragma unroll
            for (int u = 0; u < 16; ++u) wa[u] = bufB[(cc-128+u)*128 + d];
            #pragma unroll
            for (int u = 0; u < 16; u += 4) {
                const float4 a4 = *(const float4*)&agg_s[cc + u];
                a += a4.x*wa[u] + a4.y*wa[u+1] + a4.z*wa[u+2] + a4.w*wa[u+3];
            }
        }
        h1h_s[d] = fmaxf(a, 0.f);
    }
    __syncthreads();                                        // H
    if (tid == 0) {    // verbatim strictly-sequential final dot
        float a = bbh2k;
        for (int d = 0; d < 128; ++d) a += h1h_s[d] * wh2_s[d];
        out[k] = a;
    }
}

extern "C" void kernel_launch(void* const* d_in, const int* in_sizes, int n_in,
                              void* d_out, int out_size, void* d_ws, size_t ws_size,
                              hipStream_t stream) {
    const float* positions = (const float*)d_in[0];
    const float* grid      = (const float*)d_in[1];
    const float* W1  = (const float*)d_in[2];
    const float* b1  = (const float*)d_in[3];
    const float* W2  = (const float*)d_in[4];
    const float* b2  = (const float*)d_in[5];
    const float* W3  = (const float*)d_in[6];
    const float* b3  = (const float*)d_in[7];
    const float* Wn1 = (const float*)d_in[8];
    const float* bn1 = (const float*)d_in[9];
    const float* Wn2 = (const float*)d_in[10];
    const float* bn2 = (const float*)d_in[11];
    const float* Wh1 = (const float*)d_in[12];
    const float* bh1 = (const float*)d_in[13];
    const float* Wh2 = (const float*)d_in[14];
    const float* bh2 = (const float*)d_in[15];
    float* out = (float*)d_out;

    float* tpart_ws = (float*)d_ws;     // 8*256 f32, fully rewritten per call

    (void)hipFuncSetAttribute((const void*)ab_tpart,
                              hipFuncAttributeMaxDynamicSharedMemorySize,
                              AB_SMEM_BYTES);
    (void)hipFuncSetAttribute((const void*)cd_head,
                              hipFuncAttributeMaxDynamicSharedMemorySize,
                              CD_SMEM_BYTES);

    hipLaunchKernelGGL(ab_tpart, dim3(64), dim3(256), AB_SMEM_BYTES, stream,
                       positions, grid, W1, b1, W2, b2, W3, b3, Wn1, bn1,
                       tpart_ws);
    hipLaunchKernelGGL(cd_head,  dim3(4),  dim3(256), CD_SMEM_BYTES, stream,
                       Wn2, bn2, Wh1, bh1, Wh2, bh2, tpart_ws, out);
}